// Round 1
// baseline (917.207 us; speedup 1.0000x reference)
//
#include <hip/hip_runtime.h>
#include <stdint.h>

typedef short bf16x8 __attribute__((ext_vector_type(8)));
typedef float f32x4 __attribute__((ext_vector_type(4)));

static __device__ __forceinline__ unsigned short f2b(float f) {
  union { float f; unsigned int u; } v; v.f = f;
  unsigned int r = v.u + 0x7fffu + ((v.u >> 16) & 1u);
  return (unsigned short)(r >> 16);
}

// ---------- small kernels ----------

__global__ void k_deg(const int* __restrict__ ei, float* __restrict__ deg) {
  int e = blockIdx.x * blockDim.x + threadIdx.x;
  if (e < 2048) atomicAdd(&deg[ei[e]], 1.0f);
}

__global__ void k_wnorm(const int* __restrict__ ei, const float* __restrict__ deg,
                        float* __restrict__ wnorm) {
  int e = blockIdx.x * blockDim.x + threadIdx.x;
  if (e < 2048) {
    int s = ei[e], d = ei[2048 + e];
    float ds = deg[s], dd = deg[d];
    float a = ds > 0.f ? 1.f / sqrtf(fmaxf(ds, 1.f)) : 0.f;
    float b = dd > 0.f ? 1.f / sqrtf(fmaxf(dd, 1.f)) : 0.f;
    wnorm[e] = -a * b;
  }
}

__global__ void k_copy(const float* __restrict__ src, float* __restrict__ dst, int n) {
  int i = blockIdx.x * blockDim.x + threadIdx.x;
  if (i < n) dst[i] = src[i];
}

__global__ void k_lap(const int* __restrict__ ei, const float* __restrict__ wnorm,
                      const float* __restrict__ vin, float* __restrict__ y) {
  int e = blockIdx.x * blockDim.x + threadIdx.x;
  if (e < 2048) {
    int s = ei[e], d = ei[2048 + e];
    float wv = wnorm[e];
#pragma unroll
    for (int c = 0; c < 4; ++c) atomicAdd(&y[d * 4 + c], wv * vin[s * 4 + c]);
  }
}

__global__ void k_comb(const float* __restrict__ y, const float* __restrict__ prev,
                       float* __restrict__ outv, float a, float b) {
  int i = blockIdx.x * blockDim.x + threadIdx.x;
  if (i < 4096) outv[i] = a * y[i] + b * prev[i];
}

__global__ void k_cheb_out(const float* __restrict__ Tx, const float* __restrict__ cw,
                           const float* __restrict__ cb, float* __restrict__ h) {
  int n = blockIdx.x, o = threadIdx.x;
  float acc = cb[o];
#pragma unroll
  for (int k = 0; k < 5; ++k)
#pragma unroll
    for (int c = 0; c < 4; ++c)
      acc += Tx[k * 4096 + n * 4 + c] * cw[(k * 4 + c) * 192 + o];
  h[n * 192 + o] = acc;
}

__global__ void k_ea(const float* __restrict__ eattr, const float* __restrict__ ew,
                     const float* __restrict__ ebv, float* __restrict__ ea) {
  int e = blockIdx.x, o = threadIdx.x;
  float acc = ebv[o];
#pragma unroll
  for (int c = 0; c < 4; ++c) acc += eattr[e * 4 + c] * ew[c * 192 + o];
  ea[e * 192 + o] = acc;
}

__global__ void k_ln(const float* __restrict__ hin, float* __restrict__ z,
                     const float* __restrict__ g, const float* __restrict__ b, int mode) {
  __shared__ float r1[192], r2[192];
  __shared__ float mus, vars;
  int n = blockIdx.x, t = threadIdx.x;
  float v = hin[n * 192 + t];
  if (mode == 0) { z[n * 192 + t] = v; return; }
  r1[t] = v; r2[t] = v * v;
  __syncthreads();
  if (t < 96) { r1[t] += r1[t + 96]; r2[t] += r2[t + 96]; } __syncthreads();
  if (t < 48) { r1[t] += r1[t + 48]; r2[t] += r2[t + 48]; } __syncthreads();
  if (t < 24) { r1[t] += r1[t + 24]; r2[t] += r2[t + 24]; } __syncthreads();
  if (t < 12) { r1[t] += r1[t + 12]; r2[t] += r2[t + 12]; } __syncthreads();
  if (t < 6)  { r1[t] += r1[t + 6];  r2[t] += r2[t + 6];  } __syncthreads();
  if (t == 0) {
    float s1 = r1[0] + r1[1] + r1[2] + r1[3] + r1[4] + r1[5];
    float s2 = r2[0] + r2[1] + r2[2] + r2[3] + r2[4] + r2[5];
    float mu = s1 / 192.f;
    mus = mu; vars = s2 / 192.f - mu * mu;
  }
  __syncthreads();
  float o = (v - mus) * rsqrtf(vars + 1e-5f) * g[t] + b[t];
  z[n * 192 + t] = fmaxf(o, 0.f);
}

__global__ void k_gather(const int* __restrict__ ei, const float* __restrict__ z,
                         float* __restrict__ zs) {
  int e = blockIdx.x, t = threadIdx.x;
  zs[e * 192 + t] = z[ei[e] * 192 + t];
}

__global__ void k_h2(const float* __restrict__ ea, const float* __restrict__ w1,
                     const float* __restrict__ b1, float* __restrict__ h2) {
  int e = blockIdx.x, o = threadIdx.x;
  float acc = b1[o];
  const float* er = ea + e * 192;
#pragma unroll 8
  for (int j = 0; j < 192; ++j) acc += er[j] * w1[j * 192 + o];
  h2[e * 192 + o] = acc;
}

__global__ void k_msgbias(const float* __restrict__ zs, const float* __restrict__ b2,
                          float* __restrict__ msgb) {
  int e = blockIdx.x, o = threadIdx.x;
  float acc = 0.f;
  const float* zr = zs + e * 192;
#pragma unroll 8
  for (int i = 0; i < 192; ++i) acc += zr[i] * b2[i * 192 + o];
  msgb[e * 192 + o] = acc;
}

// transpose nn2_w[l] ([192][36864] f32) -> BT ([36864][192] bf16)
__global__ void k_bt(const float* __restrict__ W2, unsigned short* __restrict__ BT) {
  __shared__ float tile[64][65];
  int c0 = blockIdx.x * 64, k0 = blockIdx.y * 64;
  int tx = threadIdx.x & 63, ty = threadIdx.x >> 6;
#pragma unroll
  for (int q = 0; q < 16; ++q) {
    int k = q * 4 + ty;
    tile[k][tx] = W2[(size_t)(k0 + k) * 36864 + c0 + tx];
  }
  __syncthreads();
#pragma unroll
  for (int q = 0; q < 16; ++q) {
    int c = q * 4 + ty;
    BT[(size_t)(c0 + c) * 192 + k0 + tx] = f2b(tile[tx][c]);
  }
}

// ---------- the big fused kernel ----------
// grid (16 e-blocks, 16 i-splits), 256 threads, dynamic LDS 128000 B
// LDS: A = h2 tile [128][192] bf16, padded stride 200 ushorts (51200 B)
//      B = 2 x [96 cols][192 k] bf16, padded stride 200  (2*38400 B)
__global__ __launch_bounds__(256, 1)
void k_big(const float* __restrict__ h2, const unsigned short* __restrict__ BT,
           const float* __restrict__ zs, float* __restrict__ partial) {
  extern __shared__ unsigned short sm[];
  unsigned short* Al = sm;           // 128*200
  unsigned short* Bl = sm + 25600;   // 2 * 96*200

  const int tid = threadIdx.x;
  const int w = tid >> 6, lane = tid & 63;
  const int l15 = lane & 15, q4 = lane >> 4;
  const int eb = blockIdx.x, is = blockIdx.y;
  const int e0 = eb * 128;
  const int i0 = is * 12;

  // stage A (h2 rows) as bf16 into padded LDS
  {
    int row = tid >> 1, hf = tid & 1;
    const float* srcp = h2 + (size_t)(e0 + row) * 192 + hf * 96;
    unsigned short* dst = Al + row * 200 + hf * 96;
#pragma unroll
    for (int q = 0; q < 24; ++q) {
      float4 v = ((const float4*)srcp)[q];
      dst[q * 4 + 0] = f2b(v.x); dst[q * 4 + 1] = f2b(v.y);
      dst[q * 4 + 2] = f2b(v.z); dst[q * 4 + 3] = f2b(v.w);
    }
  }
  // prologue: load B slab for stage 0 (i=i0, o-half 0) into regs
  uint4 pref[9];
  {
    const uint4* sp = (const uint4*)(BT + (size_t)(i0 * 192) * 192);
#pragma unroll
    for (int q = 0; q < 9; ++q) pref[q] = sp[q * 256 + tid];
  }
  __syncthreads();

  const f32x4 fz = {0.f, 0.f, 0.f, 0.f};
  f32x4 msg[2][12];
#pragma unroll
  for (int a = 0; a < 2; ++a)
#pragma unroll
    for (int bq = 0; bq < 12; ++bq) msg[a][bq] = fz;

  const unsigned short* Ab = Al + (w * 32 + l15) * 200 + q4 * 8;

  for (int il = 0; il < 12; ++il) {
    float zsv[2][4];
#pragma unroll
    for (int mt = 0; mt < 2; ++mt)
#pragma unroll
      for (int r = 0; r < 4; ++r)
        zsv[mt][r] = zs[(size_t)(e0 + w * 32 + mt * 16 + q4 * 4 + r) * 192 + (i0 + il)];

#pragma unroll
    for (int oh = 0; oh < 2; ++oh) {
      const int s = il * 2 + oh;
      // commit prefetched slab to LDS buffer oh
      {
        unsigned short* Bbuf = Bl + oh * 19200;
#pragma unroll
        for (int q = 0; q < 9; ++q) {
          int flat = (q * 256 + tid) * 8;
          int col = flat / 192;
          int kk = flat - col * 192;
          *(uint4*)(Bbuf + col * 200 + kk) = pref[q];
        }
      }
      __syncthreads();
      // prefetch next slab (stays in flight through the MFMAs)
      if (s < 23) {
        int sn = s + 1;
        int inx = i0 + (sn >> 1), ohn = sn & 1;
        const uint4* sp = (const uint4*)(BT + (size_t)(inx * 192 + ohn * 96) * 192);
#pragma unroll
        for (int q = 0; q < 9; ++q) pref[q] = sp[q * 256 + tid];
      }
      // GEMM: theta_tile[128e x 96o] for this (i, o-half)
      const unsigned short* Bb = Bl + oh * 19200 + l15 * 200 + q4 * 8;
      f32x4 th[2][6];
#pragma unroll
      for (int a = 0; a < 2; ++a)
#pragma unroll
        for (int nq = 0; nq < 6; ++nq) th[a][nq] = fz;
#pragma unroll
      for (int ks = 0; ks < 6; ++ks) {
        bf16x8 a0 = *(const bf16x8*)(Ab + ks * 32);
        bf16x8 a1 = *(const bf16x8*)(Ab + 16 * 200 + ks * 32);
#pragma unroll
        for (int nt = 0; nt < 6; ++nt) {
          bf16x8 bfr = *(const bf16x8*)(Bb + nt * 16 * 200 + ks * 32);
          th[0][nt] = __builtin_amdgcn_mfma_f32_16x16x32_bf16(a0, bfr, th[0][nt], 0, 0, 0);
          th[1][nt] = __builtin_amdgcn_mfma_f32_16x16x32_bf16(a1, bfr, th[1][nt], 0, 0, 0);
        }
      }
      // contract with zs[:, i]
#pragma unroll
      for (int mt = 0; mt < 2; ++mt)
#pragma unroll
        for (int nt = 0; nt < 6; ++nt)
#pragma unroll
          for (int r = 0; r < 4; ++r)
            msg[mt][oh * 6 + nt][r] += zsv[mt][r] * th[mt][nt][r];
    }
  }
  // epilogue: write msg partials
#pragma unroll
  for (int mt = 0; mt < 2; ++mt)
#pragma unroll
    for (int nq = 0; nq < 12; ++nq) {
      int o = (nq / 6) * 96 + (nq % 6) * 16 + l15;
#pragma unroll
      for (int r = 0; r < 4; ++r) {
        int e = e0 + w * 32 + mt * 16 + q4 * 4 + r;
        partial[((size_t)is * 2048 + e) * 192 + o] = msg[mt][nq][r];
      }
    }
}

__global__ void k_reduce(const float* __restrict__ partial, const float* __restrict__ msgb,
                         const int* __restrict__ ei, float* __restrict__ agg) {
  int idx = blockIdx.x * 256 + threadIdx.x;  // < 2048*192
  int e = idx / 192, o = idx - e * 192;
  float s = msgb[idx];
#pragma unroll
  for (int is = 0; is < 16; ++is) s += partial[(size_t)is * 393216 + idx];
  atomicAdd(&agg[ei[2048 + e] * 192 + o], s);
}

__global__ void k_root(const float* __restrict__ hcur, const float* __restrict__ z,
                       const float* __restrict__ agg, const float* __restrict__ rw,
                       const float* __restrict__ cb, float* __restrict__ hnext, int res) {
  int n = blockIdx.x, o = threadIdx.x;
  float acc = agg[n * 192 + o] + cb[o];
  if (res) acc += hcur[n * 192 + o];
  const float* zr = z + n * 192;
#pragma unroll 8
  for (int j = 0; j < 192; ++j) acc += zr[j] * rw[j * 192 + o];
  hnext[n * 192 + o] = acc;
}

__global__ void k_final(const float* __restrict__ z, const float* __restrict__ ow,
                        const float* __restrict__ ob, float* __restrict__ outp) {
  int t = blockIdx.x * 256 + threadIdx.x;
  if (t >= 2048) return;
  int n = t >> 1, c = t & 1;
  float acc = ob[c];
#pragma unroll 8
  for (int j = 0; j < 192; ++j) acc += z[n * 192 + j] * ow[j * 2 + c];
  outp[t] = acc;
}

// ---------- launch ----------

extern "C" void kernel_launch(void* const* d_in, const int* in_sizes, int n_in,
                              void* d_out, int out_size, void* d_ws, size_t ws_size,
                              hipStream_t stream) {
  const float* x      = (const float*)d_in[0];
  const int*   ei     = (const int*)  d_in[1];
  const float* eattr  = (const float*)d_in[2];
  const float* cheb_w = (const float*)d_in[4];
  const float* cheb_b = (const float*)d_in[5];
  const float* eenc_w = (const float*)d_in[6];
  const float* eenc_b = (const float*)d_in[7];
  const float* nn1_w  = (const float*)d_in[8];
  const float* nn1_b  = (const float*)d_in[9];
  const float* nn2_w  = (const float*)d_in[10];
  const float* nn2_b  = (const float*)d_in[11];
  const float* root_w = (const float*)d_in[12];
  const float* conv_b = (const float*)d_in[13];
  const float* ln_g   = (const float*)d_in[14];
  const float* ln_bb  = (const float*)d_in[15];
  const float* out_w  = (const float*)d_in[16];
  const float* out_b  = (const float*)d_in[17];
  float* outp = (float*)d_out;
  (void)in_sizes; (void)n_in; (void)out_size; (void)ws_size;

  char* p = (char*)d_ws;
  unsigned short* BT = (unsigned short*)p; p += (size_t)36864 * 192 * 2;
  float* deg   = (float*)p; p += 1024 * 4;
  float* wnorm = (float*)p; p += 2048 * 4;
  float* Tx    = (float*)p; p += 5 * 4096 * 4;
  float* y     = (float*)p; p += 4096 * 4;
  float* h     = (float*)p; p += 196608 * 4;
  float* hB    = (float*)p; p += 196608 * 4;
  float* z     = (float*)p; p += 196608 * 4;
  float* ea    = (float*)p; p += 393216 * 4;
  float* zsb   = (float*)p; p += 393216 * 4;
  float* h2b   = (float*)p; p += 393216 * 4;
  float* msgb  = (float*)p; p += 393216 * 4;
  float* agg   = (float*)p; p += 196608 * 4;
  float* part  = (float*)p; p += (size_t)16 * 393216 * 4;

  hipFuncSetAttribute(reinterpret_cast<const void*>(&k_big),
                      hipFuncAttributeMaxDynamicSharedMemorySize, 131072);

  // ---- ChebConv prep ----
  hipMemsetAsync(deg, 0, 1024 * 4, stream);
  k_deg<<<8, 256, 0, stream>>>(ei, deg);
  k_wnorm<<<8, 256, 0, stream>>>(ei, deg, wnorm);
  k_copy<<<16, 256, 0, stream>>>(x, Tx, 4096);
  for (int rec = 0; rec < 4; ++rec) {
    hipMemsetAsync(y, 0, 4096 * 4, stream);
    k_lap<<<8, 256, 0, stream>>>(ei, wnorm, Tx + rec * 4096, y);
    const float* prev = (rec == 0) ? Tx : Tx + (rec - 1) * 4096;
    k_comb<<<16, 256, 0, stream>>>(y, prev, Tx + (rec + 1) * 4096,
                                   (rec == 0) ? 1.f : 2.f, (rec == 0) ? 0.f : -1.f);
  }
  k_cheb_out<<<1024, 192, 0, stream>>>(Tx, cheb_w, cheb_b, h);
  k_ea<<<2048, 192, 0, stream>>>(eattr, eenc_w, eenc_b, ea);

  // ---- NNConv layers ----
  float* hcur = h; float* hnext = hB;
  for (int l = 0; l < 4; ++l) {
    k_ln<<<1024, 192, 0, stream>>>(hcur, z, ln_g + l * 192, ln_bb + l * 192, (l == 0) ? 0 : 1);
    k_gather<<<2048, 192, 0, stream>>>(ei, z, zsb);
    k_h2<<<2048, 192, 0, stream>>>(ea, nn1_w + (size_t)l * 36864, nn1_b + l * 192, h2b);
    k_msgbias<<<2048, 192, 0, stream>>>(zsb, nn2_b + (size_t)l * 36864, msgb);
    k_bt<<<dim3(576, 3), 256, 0, stream>>>(nn2_w + (size_t)l * 7077888, BT);
    hipMemsetAsync(agg, 0, 196608 * 4, stream);
    k_big<<<dim3(16, 16), 256, 128000, stream>>>(h2b, BT, zsb, part);
    k_reduce<<<1536, 256, 0, stream>>>(part, msgb, ei, agg);
    k_root<<<1024, 192, 0, stream>>>(hcur, z, agg, root_w + (size_t)l * 36864,
                                     conv_b + l * 192, hnext, (l == 0) ? 0 : 1);
    float* t = hcur; hcur = hnext; hnext = t;
  }
  // ---- final head ----
  k_ln<<<1024, 192, 0, stream>>>(hcur, z, ln_g, ln_bb, 1);
  k_final<<<8, 256, 0, stream>>>(z, out_w, out_b, outp);
}

// Round 2
// 696.013 us; speedup vs baseline: 1.3178x; 1.3178x over previous
//
#include <hip/hip_runtime.h>
#include <stdint.h>

typedef _Float16 half8 __attribute__((ext_vector_type(8)));
typedef float f32x4 __attribute__((ext_vector_type(4)));

typedef const __attribute__((address_space(1))) void* gptr_t;
typedef __attribute__((address_space(3))) void* lptr_t;
static __device__ __forceinline__ void gll16(const void* g, void* l) {
  __builtin_amdgcn_global_load_lds((gptr_t)(unsigned long long)g,
                                   (lptr_t)(unsigned int)(unsigned long long)l,
                                   16, 0, 0);
}

// ---------------- Cheb: everything fused into one block ----------------
__global__ __launch_bounds__(1024)
void k_cheb_all(const float* __restrict__ x, const int* __restrict__ ei,
                float* __restrict__ Tx) {
  __shared__ float deg[1024];
  __shared__ float wn[2048];
  __shared__ float T0[4096], T1[4096], yv[4096];
  int t = threadIdx.x;
  deg[t] = 0.f;
  __syncthreads();
  atomicAdd(&deg[ei[t]], 1.f);
  atomicAdd(&deg[ei[1024 + t]], 1.f);
  __syncthreads();
  for (int e = t; e < 2048; e += 1024) {
    int s = ei[e], d = ei[2048 + e];
    float ds = deg[s], dd = deg[d];
    float a = ds > 0.f ? 1.f / sqrtf(fmaxf(ds, 1.f)) : 0.f;
    float b = dd > 0.f ? 1.f / sqrtf(fmaxf(dd, 1.f)) : 0.f;
    wn[e] = -a * b;
  }
  float4 xv = ((const float4*)x)[t];
  ((float4*)T0)[t] = xv;
  ((float4*)Tx)[t] = xv;
  __syncthreads();
  float* cur = T0; float* nxt = T1;
  for (int rec = 0; rec < 4; ++rec) {
    ((float4*)yv)[t] = make_float4(0.f, 0.f, 0.f, 0.f);
    __syncthreads();
    for (int e = t; e < 2048; e += 1024) {
      int s = ei[e], d = ei[2048 + e];
      float wv = wn[e];
#pragma unroll
      for (int c = 0; c < 4; ++c) atomicAdd(&yv[d * 4 + c], wv * cur[s * 4 + c]);
    }
    __syncthreads();
    float a = (rec == 0) ? 1.f : 2.f;
    float4 y4 = ((float4*)yv)[t];
    float4 p4 = ((float4*)nxt)[t];
    float4 n4;
    n4.x = a * y4.x - (rec ? p4.x : 0.f);
    n4.y = a * y4.y - (rec ? p4.y : 0.f);
    n4.z = a * y4.z - (rec ? p4.z : 0.f);
    n4.w = a * y4.w - (rec ? p4.w : 0.f);
    ((float4*)nxt)[t] = n4;
    ((float4*)(Tx + (rec + 1) * 4096))[t] = n4;
    __syncthreads();
    float* tmp = cur; cur = nxt; nxt = tmp;
  }
}

__global__ void k_cheb_out(const float* __restrict__ Tx, const float* __restrict__ cw,
                           const float* __restrict__ cb, float* __restrict__ h) {
  int n = blockIdx.x, o = threadIdx.x;
  float acc = cb[o];
#pragma unroll
  for (int k = 0; k < 5; ++k)
#pragma unroll
    for (int c = 0; c < 4; ++c)
      acc += Tx[k * 4096 + n * 4 + c] * cw[(k * 4 + c) * 192 + o];
  h[n * 192 + o] = acc;
}

__global__ void k_ea(const float* __restrict__ eattr, const float* __restrict__ ew,
                     const float* __restrict__ ebv, float* __restrict__ ea) {
  int e = blockIdx.x, o = threadIdx.x;
  float acc = ebv[o];
#pragma unroll
  for (int c = 0; c < 4; ++c) acc += eattr[e * 4 + c] * ew[c * 192 + o];
  ea[e * 192 + o] = acc;
}

__global__ void k_ln(const float* __restrict__ hin, float* __restrict__ z,
                     const float* __restrict__ g, const float* __restrict__ b, int mode) {
  __shared__ float r1[192], r2[192];
  __shared__ float mus, vars;
  int n = blockIdx.x, t = threadIdx.x;
  float v = hin[n * 192 + t];
  if (mode == 0) { z[n * 192 + t] = v; return; }
  r1[t] = v; r2[t] = v * v;
  __syncthreads();
  if (t < 96) { r1[t] += r1[t + 96]; r2[t] += r2[t + 96]; } __syncthreads();
  if (t < 48) { r1[t] += r1[t + 48]; r2[t] += r2[t + 48]; } __syncthreads();
  if (t < 24) { r1[t] += r1[t + 24]; r2[t] += r2[t + 24]; } __syncthreads();
  if (t < 12) { r1[t] += r1[t + 12]; r2[t] += r2[t + 12]; } __syncthreads();
  if (t < 6)  { r1[t] += r1[t + 6];  r2[t] += r2[t + 6];  } __syncthreads();
  if (t == 0) {
    float s1 = r1[0] + r1[1] + r1[2] + r1[3] + r1[4] + r1[5];
    float s2 = r2[0] + r2[1] + r2[2] + r2[3] + r2[4] + r2[5];
    float mu = s1 / 192.f;
    mus = mu; vars = s2 / 192.f - mu * mu;
  }
  __syncthreads();
  float o = (v - mus) * rsqrtf(vars + 1e-5f) * g[t] + b[t];
  z[n * 192 + t] = fmaxf(o, 0.f);
}

// gather z rows by src and emit transposed f16 zsT[i][e]
__global__ void k_gatherT(const int* __restrict__ ei, const float* __restrict__ z,
                          _Float16* __restrict__ zsT) {
  __shared__ float tl[64 * 193];
  int e0 = blockIdx.x * 64, t = threadIdx.x;
#pragma unroll
  for (int it = 0; it < 48; ++it) {
    int idx = it * 256 + t;          // 64*192
    int es = idx / 192, i = idx - es * 192;
    tl[es * 193 + i] = z[(size_t)ei[e0 + es] * 192 + i];
  }
  __syncthreads();
#pragma unroll
  for (int it = 0; it < 48; ++it) {
    int idx = it * 256 + t;
    int i = idx >> 6, es = idx & 63;  // 192 x 64
    zsT[(size_t)i * 2048 + e0 + es] = (_Float16)tl[es * 193 + i];
  }
}

// fused: h2 = ea@nn1+b1 (emitted f16 in k-chunk-major layout) and msgb = zs@B2
__global__ void k_h2pm(const float* __restrict__ ea, const float* __restrict__ w1,
                       const float* __restrict__ b1, const float* __restrict__ z,
                       const int* __restrict__ ei, const float* __restrict__ b2,
                       _Float16* __restrict__ h2p, float* __restrict__ msgb) {
  int e = blockIdx.x, o = threadIdx.x;
  const float* er = ea + e * 192;
  float acc = b1[o];
#pragma unroll 8
  for (int j = 0; j < 192; ++j) acc += er[j] * w1[j * 192 + o];
  h2p[((size_t)(o >> 3) * 2048 + e) * 8 + (o & 7)] = (_Float16)acc;
  const float* zr = z + (size_t)ei[e] * 192;
  float m = 0.f;
#pragma unroll 8
  for (int i = 0; i < 192; ++i) m += zr[i] * b2[i * 192 + o];
  msgb[e * 192 + o] = m;
}

// W2 [192 k][36864 (i*192+o)] f32 -> BTp f16, halfs offset ((i*24+ck)*192+o)*8+j, kk=ck*8+j
__global__ void k_bt2(const float* __restrict__ W2, _Float16* __restrict__ BTp) {
  __shared__ float tl[192 * 65];
  int i = blockIdx.x, o0 = blockIdx.y * 64, t = threadIdx.x;
#pragma unroll
  for (int it = 0; it < 48; ++it) {
    int idx = it * 256 + t;          // 192*64
    int kk = idx >> 6, o = idx & 63;
    tl[kk * 65 + o] = W2[(size_t)kk * 36864 + i * 192 + o0 + o];
  }
  __syncthreads();
#pragma unroll
  for (int it = 0; it < 6; ++it) {
    int idx = it * 256 + t;          // 24*64
    int ck = idx >> 6, o = idx & 63;
    union { _Float16 h[8]; uint4 v; } u;
#pragma unroll
    for (int j = 0; j < 8; ++j) u.h[j] = (_Float16)tl[(ck * 8 + j) * 65 + o];
    *(uint4*)(BTp + ((size_t)(i * 24 + ck) * 192 + o0 + o) * 8) = u.v;
  }
}

// ---------------- the big fused GEMM ----------------
// C[2048,192] = G @ B, K=36864; A-frags = h2 (LDS, staged once) * zs scalar.
// grid (16 m-blocks, 32 k-chunks), 512 threads, dyn LDS 73728 B.
__global__ __launch_bounds__(512, 4)
void k_big2(const _Float16* __restrict__ h2p, const _Float16* __restrict__ BTp,
            const _Float16* __restrict__ zsT, _Float16* __restrict__ partial) {
  extern __shared__ _Float16 sm[];
  _Float16* Al = sm;           // 24 chunks * 128 rows * 8 = 24576 halfs
  _Float16* Bl = sm + 24576;   // 2 * 6144 halfs

  const int tid = threadIdx.x;
  const int w = tid >> 6, lane = tid & 63;
  const int l15 = lane & 15, q4 = lane >> 4;
  const int wm = w >> 2, wn = w & 3;       // 2 x 4 wave grid
  const int e0 = blockIdx.x * 128;
  const int s = blockIdx.y;
  const int i0 = s * 6;
  const int sg0 = s * 36;

  // stage A tile: 48 KB, lane-linear, 6 wave-issues
#pragma unroll
  for (int t = 0; t < 6; ++t) {
    int fo = (t * 8 + w) * 1024 + lane * 16;   // byte offset, within one 2 KB q-chunk
    int q = fo >> 11;
    const _Float16* g = h2p + (size_t)q * 16384 + (size_t)e0 * 8 + ((fo & 2047) >> 1);
    gll16(g, (char*)Al + fo);
  }
  // stage B chunk 0 into buf 0
  {
    const char* g = (const char*)BTp + (size_t)sg0 * 12288 + w * 1024 + lane * 16;
    char* l = (char*)Bl + w * 1024 + lane * 16;
    gll16(g, l);
    if (w < 4) gll16(g + 8192, l + 8192);
  }
  _Float16 zcur[4], znxt[4];
#pragma unroll
  for (int mt = 0; mt < 4; ++mt)
    zcur[mt] = zsT[(size_t)i0 * 2048 + e0 + wm * 64 + mt * 16 + l15];
  __syncthreads();

  f32x4 acc[4][3] = {};
  int buf = 0;

  for (int ip = 0; ip < 6; ++ip) {
    if (ip < 5) {
#pragma unroll
      for (int mt = 0; mt < 4; ++mt)
        znxt[mt] = zsT[(size_t)(i0 + ip + 1) * 2048 + e0 + wm * 64 + mt * 16 + l15];
    }
    half8 zv[4];
#pragma unroll
    for (int mt = 0; mt < 4; ++mt) {
      _Float16 zc = zcur[mt];
      zv[mt] = (half8){zc, zc, zc, zc, zc, zc, zc, zc};
    }
#pragma unroll
    for (int k6 = 0; k6 < 6; ++k6) {
      int ks = ip * 6 + k6;
      if (ks < 35) {  // prefetch next B chunk into the other buffer
        const char* g = (const char*)BTp + (size_t)(sg0 + ks + 1) * 12288 + w * 1024 + lane * 16;
        char* l = (char*)Bl + (buf ^ 1) * 12288 + w * 1024 + lane * 16;
        gll16(g, l);
        if (w < 4) gll16(g + 8192, l + 8192);
      }
      half8 av[4];
#pragma unroll
      for (int mt = 0; mt < 4; ++mt) {
        half8 hv = *(const half8*)(Al + (((k6 * 4 + q4) * 128) + wm * 64 + mt * 16 + l15) * 8);
        av[mt] = hv * zv[mt];
      }
#pragma unroll
      for (int nt = 0; nt < 3; ++nt) {
        half8 bv = *(const half8*)(Bl + buf * 6144 + ((q4 * 192) + wn * 48 + nt * 16 + l15) * 8);
#pragma unroll
        for (int mt = 0; mt < 4; ++mt)
          acc[mt][nt] = __builtin_amdgcn_mfma_f32_16x16x32_f16(av[mt], bv, acc[mt][nt], 0, 0, 0);
      }
      __syncthreads();
      buf ^= 1;
    }
#pragma unroll
    for (int mt = 0; mt < 4; ++mt) zcur[mt] = znxt[mt];
  }

  // epilogue: f16 partials, coalesced within 16-lane groups
#pragma unroll
  for (int mt = 0; mt < 4; ++mt)
#pragma unroll
    for (int nt = 0; nt < 3; ++nt) {
      int o = wn * 48 + nt * 16 + l15;
#pragma unroll
      for (int r = 0; r < 4; ++r) {
        int e = e0 + wm * 64 + mt * 16 + q4 * 4 + r;
        partial[((size_t)s * 2048 + e) * 192 + o] = (_Float16)acc[mt][nt][r];
      }
    }
}

__global__ void k_reduce(const _Float16* __restrict__ partial, const float* __restrict__ msgb,
                         const int* __restrict__ ei, float* __restrict__ agg) {
  int idx = blockIdx.x * 256 + threadIdx.x;  // < 2048*192
  int e = idx / 192, o = idx - e * 192;
  float ssum = msgb[idx];
#pragma unroll
  for (int sc = 0; sc < 32; ++sc) ssum += (float)partial[(size_t)sc * 393216 + idx];
  atomicAdd(&agg[ei[2048 + e] * 192 + o], ssum);
}

__global__ void k_root(const float* __restrict__ hcur, const float* __restrict__ z,
                       const float* __restrict__ agg, const float* __restrict__ rw,
                       const float* __restrict__ cb, float* __restrict__ hnext, int res) {
  int n = blockIdx.x, o = threadIdx.x;
  float acc = agg[n * 192 + o] + cb[o];
  if (res) acc += hcur[n * 192 + o];
  const float* zr = z + n * 192;
#pragma unroll 8
  for (int j = 0; j < 192; ++j) acc += zr[j] * rw[j * 192 + o];
  hnext[n * 192 + o] = acc;
}

__global__ void k_final(const float* __restrict__ z, const float* __restrict__ ow,
                        const float* __restrict__ ob, float* __restrict__ outp) {
  int t = blockIdx.x * 256 + threadIdx.x;
  if (t >= 2048) return;
  int n = t >> 1, c = t & 1;
  float acc = ob[c];
#pragma unroll 8
  for (int j = 0; j < 192; ++j) acc += z[n * 192 + j] * ow[j * 2 + c];
  outp[t] = acc;
}

// ---------------- launch ----------------
extern "C" void kernel_launch(void* const* d_in, const int* in_sizes, int n_in,
                              void* d_out, int out_size, void* d_ws, size_t ws_size,
                              hipStream_t stream) {
  const float* x      = (const float*)d_in[0];
  const int*   ei     = (const int*)  d_in[1];
  const float* eattr  = (const float*)d_in[2];
  const float* cheb_w = (const float*)d_in[4];
  const float* cheb_b = (const float*)d_in[5];
  const float* eenc_w = (const float*)d_in[6];
  const float* eenc_b = (const float*)d_in[7];
  const float* nn1_w  = (const float*)d_in[8];
  const float* nn1_b  = (const float*)d_in[9];
  const float* nn2_w  = (const float*)d_in[10];
  const float* nn2_b  = (const float*)d_in[11];
  const float* root_w = (const float*)d_in[12];
  const float* conv_b = (const float*)d_in[13];
  const float* ln_g   = (const float*)d_in[14];
  const float* ln_bb  = (const float*)d_in[15];
  const float* out_w  = (const float*)d_in[16];
  const float* out_b  = (const float*)d_in[17];
  float* outp = (float*)d_out;
  (void)in_sizes; (void)n_in; (void)out_size; (void)ws_size;

  char* p = (char*)d_ws;
  _Float16* BTp  = (_Float16*)p; p += (size_t)4608 * 192 * 8 * 2;       // 14,155,776
  _Float16* h2p  = (_Float16*)p; p += (size_t)24 * 2048 * 8 * 2;        // 786,432
  _Float16* zsT  = (_Float16*)p; p += (size_t)192 * 2048 * 2;           // 786,432
  _Float16* part = (_Float16*)p; p += (size_t)32 * 2048 * 192 * 2;      // 25,165,824
  float* Tx   = (float*)p; p += 5 * 4096 * 4;
  float* h    = (float*)p; p += 196608 * 4;
  float* hB   = (float*)p; p += 196608 * 4;
  float* z    = (float*)p; p += 196608 * 4;
  float* ea   = (float*)p; p += 393216 * 4;
  float* msgb = (float*)p; p += 393216 * 4;
  float* agg  = (float*)p; p += 196608 * 4;

  hipFuncSetAttribute(reinterpret_cast<const void*>(&k_big2),
                      hipFuncAttributeMaxDynamicSharedMemorySize, 73728);

  k_cheb_all<<<1, 1024, 0, stream>>>(x, ei, Tx);
  k_cheb_out<<<1024, 192, 0, stream>>>(Tx, cheb_w, cheb_b, h);
  k_ea<<<2048, 192, 0, stream>>>(eattr, eenc_w, eenc_b, ea);

  float* hcur = h; float* hnext = hB;
  for (int l = 0; l < 4; ++l) {
    k_ln<<<1024, 192, 0, stream>>>(hcur, z, ln_g + l * 192, ln_bb + l * 192, (l == 0) ? 0 : 1);
    k_gatherT<<<32, 256, 0, stream>>>(ei, z, zsT);
    k_h2pm<<<2048, 192, 0, stream>>>(ea, nn1_w + (size_t)l * 36864, nn1_b + l * 192,
                                     z, ei, nn2_b + (size_t)l * 36864, h2p, msgb);
    k_bt2<<<dim3(192, 3), 256, 0, stream>>>(nn2_w + (size_t)l * 7077888, BTp);
    hipMemsetAsync(agg, 0, 196608 * 4, stream);
    k_big2<<<dim3(16, 32), 512, 73728, stream>>>(h2p, BTp, zsT, part);
    k_reduce<<<1536, 256, 0, stream>>>(part, msgb, ei, agg);
    k_root<<<1024, 192, 0, stream>>>(hcur, z, agg, root_w + (size_t)l * 36864,
                                     conv_b + l * 192, hnext, (l == 0) ? 0 : 1);
    float* t = hcur; hcur = hnext; hnext = t;
  }
  k_ln<<<1024, 192, 0, stream>>>(hcur, z, ln_g, ln_bb, 1);
  k_final<<<8, 256, 0, stream>>>(z, out_w, out_b, outp);
}